// Round 5
// baseline (100.972 us; speedup 1.0000x reference)
//
#include <hip/hip_runtime.h>

// Problem constants (from reference)
#define SEQLEN  128
#define NKV     8
#define BATCH   8
#define HD      128
#define MAXSEQ  4096

typedef float f32x4 __attribute__((ext_vector_type(4)));

constexpr int       HD4     = HD / 4;                                   // 32 float4 per head row
constexpr long long HALF_F4 = (long long)BATCH * NKV * MAXSEQ * HD4;    // 2^23 f4 per tensor
constexpr int       UNROLL  = 8;

// R3 (97.0 us) + ILP actually enforced this time. R4's 4-way batch was
// re-serialized by the compiler (VGPR_Count=12 proves loads were not kept in
// flight). Fix: asm "+v" keep-alive on all batched values between the load
// loop and the store loop -> compiler must materialize all 8 f32x4
// simultaneously (32 data VGPRs) and issue all loads before any store.
// Everything else (mapping, nt stores, grid 2048x256) identical to R3.

__global__ __launch_bounds__(256) void kv_update_kernel(
    const f32x4* __restrict__ xk,     // [SEQLEN][NKV][BATCH][HD]
    const f32x4* __restrict__ xv,
    const f32x4* __restrict__ kpast,  // [BATCH][NKV][MAXSEQ][HD]
    const f32x4* __restrict__ vpast,
    const int*   __restrict__ plen_ptr,
    f32x4*       __restrict__ out)    // new_k ++ new_v, flat
{
    const int plen = *plen_ptr;
    const long long total  = 2 * HALF_F4;                          // 2^24 f4
    const long long stride = (long long)gridDim.x * blockDim.x;    // 2^19
    const long long i0     = (long long)blockIdx.x * blockDim.x + threadIdx.x;

    // total / (UNROLL*stride) = 4 exact macro-iterations; full coverage.
    for (long long i = i0; i < total; i += (long long)UNROLL * stride) {
        f32x4 v[UNROLL];

        #pragma unroll
        for (int u = 0; u < UNROLL; ++u) {
            const long long e = i + (long long)u * stride;
            long long rem = e;
            const f32x4* past = kpast;
            const f32x4* xnew = xk;
            if (rem >= HALF_F4) { rem -= HALF_F4; past = vpast; xnew = xv; }

            // rem = ((b*NKV + h)*MAXSEQ + s)*HD4 + d4
            const int       d4  = (int)(rem & (HD4 - 1));      // % 32
            const long long row = rem >> 5;                    // / 32
            const int       s   = (int)(row & (MAXSEQ - 1));   // % 4096
            const int       bh  = (int)(row >> 12);            // / 4096
            const int       h   = bh & (NKV - 1);
            const int       b   = bh >> 3;
            const int       sl  = s - plen;

            const f32x4* src = ((unsigned)sl < (unsigned)SEQLEN)
                ? &xnew[(long long)((sl * NKV + h) * BATCH + b) * HD4 + d4]
                : &past[rem];
            v[u] = *src;
        }

        // Force all 8 values live at once: reads must all issue before any
        // store below. "+v" (read-write) stops the compiler from sinking
        // loads past stores to save registers (what killed R4).
        #pragma unroll
        for (int u = 0; u < UNROLL; ++u) {
            asm volatile("" : "+v"(v[u]));
        }

        #pragma unroll
        for (int u = 0; u < UNROLL; ++u) {
            __builtin_nontemporal_store(v[u], &out[i + (long long)u * stride]);
        }
    }
}

extern "C" void kernel_launch(void* const* d_in, const int* in_sizes, int n_in,
                              void* d_out, int out_size, void* d_ws, size_t ws_size,
                              hipStream_t stream) {
    const f32x4* xk    = (const f32x4*)d_in[0];
    const f32x4* xv    = (const f32x4*)d_in[1];
    const f32x4* kpast = (const f32x4*)d_in[2];
    const f32x4* vpast = (const f32x4*)d_in[3];
    const int*   plen  = (const int*)d_in[4];
    f32x4*       out   = (f32x4*)d_out;

    dim3 grid(2048), block(256);   // same as R3: 2^19 threads, 32 f4/thread
    kv_update_kernel<<<grid, block, 0, stream>>>(xk, xv, kpast, vpast, plen, out);
}

// Round 6
// 91.751 us; speedup vs baseline: 1.1005x; 1.1005x over previous
//
#include <hip/hip_runtime.h>

// Problem constants (from reference)
#define SEQLEN  128
#define NKV     8
#define BATCH   8
#define HD      128
#define MAXSEQ  4096

typedef float f32x4 __attribute__((ext_vector_type(4)));

constexpr int       HD4     = HD / 4;                                   // 32 float4 per head row
constexpr long long HALF_F4 = (long long)BATCH * NKV * MAXSEQ * HD4;    // 2^23 f4 per tensor

// Exact R3 kernel (97.0 us best) with ONE change: grid 2048 -> 8192 blocks.
// R4/R5 refuted per-thread MLP as the limiter; remaining theory is dispatch
// tail / load imbalance from launching exactly 8192 waves into 8192 slots
// with no backfill. 4x oversubscription gives the scheduler rebalance room
// and shrinks the tail quantum from ~25us (32 iters/thread) to ~6us.

__global__ __launch_bounds__(256) void kv_update_kernel(
    const f32x4* __restrict__ xk,     // [SEQLEN][NKV][BATCH][HD]
    const f32x4* __restrict__ xv,
    const f32x4* __restrict__ kpast,  // [BATCH][NKV][MAXSEQ][HD]
    const f32x4* __restrict__ vpast,
    const int*   __restrict__ plen_ptr,
    f32x4*       __restrict__ out)    // new_k ++ new_v, flat
{
    const int plen = *plen_ptr;        // uniform address -> broadcast, cheap
    const long long total  = 2 * HALF_F4;
    const long long stride = (long long)gridDim.x * blockDim.x;

    for (long long i = (long long)blockIdx.x * blockDim.x + threadIdx.x;
         i < total; i += stride) {

        long long rem = i;
        const f32x4* past;
        const f32x4* xnew;
        if (rem >= HALF_F4) { rem -= HALF_F4; past = vpast; xnew = xv; }
        else                {                  past = kpast; xnew = xk; }

        // rem = ((b*NKV + h)*MAXSEQ + s)*HD4 + d4
        const int       d4  = (int)(rem & (HD4 - 1));      // % 32
        const long long row = rem >> 5;                    // / 32
        const int       s   = (int)(row & (MAXSEQ - 1));   // % 4096
        const int       bh  = (int)(row >> 12);            // / 4096
        const int       h   = bh & (NKV - 1);
        const int       b   = bh >> 3;

        const int sl = s - plen;
        f32x4 val;
        if ((unsigned)sl < (unsigned)SEQLEN) {
            // xk[sl][h][b][d]: flat float4 index = ((sl*NKV + h)*BATCH + b)*HD4 + d4
            val = xnew[(long long)((sl * NKV + h) * BATCH + b) * HD4 + d4];
        } else {
            val = past[rem];           // same flat offset -> perfectly coalesced
        }
        __builtin_nontemporal_store(val, &out[i]);
    }
}

extern "C" void kernel_launch(void* const* d_in, const int* in_sizes, int n_in,
                              void* d_out, int out_size, void* d_ws, size_t ws_size,
                              hipStream_t stream) {
    const f32x4* xk    = (const f32x4*)d_in[0];
    const f32x4* xv    = (const f32x4*)d_in[1];
    const f32x4* kpast = (const f32x4*)d_in[2];
    const f32x4* vpast = (const f32x4*)d_in[3];
    const int*   plen  = (const int*)d_in[4];
    f32x4*       out   = (f32x4*)d_out;

    dim3 grid(8192), block(256);   // 4x wave-slot oversubscription; 8 f4/thread
    kv_update_kernel<<<grid, block, 0, stream>>>(xk, xv, kpast, vpast, plen, out);
}

// Round 7
// 83.011 us; speedup vs baseline: 1.2164x; 1.1053x over previous
//
#include <hip/hip_runtime.h>

// Problem constants (from reference)
#define SEQLEN  128
#define NKV     8
#define BATCH   8
#define HD      128
#define MAXSEQ  4096

typedef float f32x4 __attribute__((ext_vector_type(4)));

constexpr int       HD4     = HD / 4;                                   // 32 float4 per head row
constexpr long long HALF_F4 = (long long)BATCH * NKV * MAXSEQ * HD4;    // 2^23 f4 per tensor

// R6 kernel (91.75 us) with ONE change: grid 8192 -> 32768 blocks
// (2 f4-iterations/thread). R6 confirmed oversubscription/backfill as the
// live lever (+5.4%); this shrinks the tail quantum from ~11us to ~3us.
// Everything else (mapping, nt stores, block=256) identical.

__global__ __launch_bounds__(256) void kv_update_kernel(
    const f32x4* __restrict__ xk,     // [SEQLEN][NKV][BATCH][HD]
    const f32x4* __restrict__ xv,
    const f32x4* __restrict__ kpast,  // [BATCH][NKV][MAXSEQ][HD]
    const f32x4* __restrict__ vpast,
    const int*   __restrict__ plen_ptr,
    f32x4*       __restrict__ out)    // new_k ++ new_v, flat
{
    const int plen = *plen_ptr;        // uniform address -> broadcast, cheap
    const long long total  = 2 * HALF_F4;
    const long long stride = (long long)gridDim.x * blockDim.x;

    for (long long i = (long long)blockIdx.x * blockDim.x + threadIdx.x;
         i < total; i += stride) {

        long long rem = i;
        const f32x4* past;
        const f32x4* xnew;
        if (rem >= HALF_F4) { rem -= HALF_F4; past = vpast; xnew = xv; }
        else                {                  past = kpast; xnew = xk; }

        // rem = ((b*NKV + h)*MAXSEQ + s)*HD4 + d4
        const int       d4  = (int)(rem & (HD4 - 1));      // % 32
        const long long row = rem >> 5;                    // / 32
        const int       s   = (int)(row & (MAXSEQ - 1));   // % 4096
        const int       bh  = (int)(row >> 12);            // / 4096
        const int       h   = bh & (NKV - 1);
        const int       b   = bh >> 3;

        const int sl = s - plen;
        f32x4 val;
        if ((unsigned)sl < (unsigned)SEQLEN) {
            // xk[sl][h][b][d]: flat float4 index = ((sl*NKV + h)*BATCH + b)*HD4 + d4
            val = xnew[(long long)((sl * NKV + h) * BATCH + b) * HD4 + d4];
        } else {
            val = past[rem];           // same flat offset -> perfectly coalesced
        }
        __builtin_nontemporal_store(val, &out[i]);
    }
}

extern "C" void kernel_launch(void* const* d_in, const int* in_sizes, int n_in,
                              void* d_out, int out_size, void* d_ws, size_t ws_size,
                              hipStream_t stream) {
    const f32x4* xk    = (const f32x4*)d_in[0];
    const f32x4* xv    = (const f32x4*)d_in[1];
    const f32x4* kpast = (const f32x4*)d_in[2];
    const f32x4* vpast = (const f32x4*)d_in[3];
    const int*   plen  = (const int*)d_in[4];
    f32x4*       out   = (f32x4*)d_out;

    dim3 grid(32768), block(256);   // 16x oversubscription; 2 f4/thread
    kv_update_kernel<<<grid, block, 0, stream>>>(xk, xv, kpast, vpast, plen, out);
}

// Round 8
// 81.994 us; speedup vs baseline: 1.2315x; 1.0124x over previous
//
#include <hip/hip_runtime.h>

// Problem constants (from reference)
#define SEQLEN  128
#define NKV     8
#define BATCH   8
#define HD      128
#define MAXSEQ  4096

typedef float f32x4 __attribute__((ext_vector_type(4)));

constexpr int      HD4     = HD / 4;                                  // 32 float4 per head row
constexpr unsigned HALF_F4 = (unsigned)BATCH * NKV * MAXSEQ * HD4;    // 2^23 f4 per tensor

// R7 (83.0 us) with ONE change: grid 32768 -> 65536 blocks = exactly 1 f4
// per thread; the grid-stride loop degenerates to straight-line code.
// Oversubscription trend: 2048->97us, 8192->91.8us, 32768->83.0us. This is
// the lever's endpoint at f4 granularity. nt stores, mapping unchanged.

__global__ __launch_bounds__(256) void kv_update_kernel(
    const f32x4* __restrict__ xk,     // [SEQLEN][NKV][BATCH][HD]
    const f32x4* __restrict__ xv,
    const f32x4* __restrict__ kpast,  // [BATCH][NKV][MAXSEQ][HD]
    const f32x4* __restrict__ vpast,
    const int*   __restrict__ plen_ptr,
    f32x4*       __restrict__ out)    // new_k ++ new_v, flat
{
    const unsigned i = blockIdx.x * 256u + threadIdx.x;   // [0, 2^24)
    const int plen = *plen_ptr;

    unsigned rem = i;
    const f32x4* past = kpast;
    const f32x4* xnew = xk;
    if (rem >= HALF_F4) { rem -= HALF_F4; past = vpast; xnew = xv; }

    // rem = ((b*NKV + h)*MAXSEQ + s)*HD4 + d4
    const unsigned d4  = rem & (HD4 - 1);          // % 32
    const unsigned row = rem >> 5;                 // / 32
    const unsigned s   = row & (MAXSEQ - 1);       // % 4096
    const unsigned bh  = row >> 12;                // / 4096
    const unsigned h   = bh & (NKV - 1);
    const unsigned b   = bh >> 3;

    const int sl = (int)s - plen;
    f32x4 val;
    if ((unsigned)sl < (unsigned)SEQLEN) {
        // xk[sl][h][b][d]: flat f4 index = ((sl*NKV + h)*BATCH + b)*HD4 + d4
        val = xnew[(((unsigned)sl * NKV + h) * BATCH + b) * HD4 + d4];
    } else {
        val = past[rem];               // same flat offset -> perfectly coalesced
    }
    __builtin_nontemporal_store(val, &out[i]);
}

extern "C" void kernel_launch(void* const* d_in, const int* in_sizes, int n_in,
                              void* d_out, int out_size, void* d_ws, size_t ws_size,
                              hipStream_t stream) {
    const f32x4* xk    = (const f32x4*)d_in[0];
    const f32x4* xv    = (const f32x4*)d_in[1];
    const f32x4* kpast = (const f32x4*)d_in[2];
    const f32x4* vpast = (const f32x4*)d_in[3];
    const int*   plen  = (const int*)d_in[4];
    f32x4*       out   = (f32x4*)d_out;

    dim3 grid(65536), block(256);   // 1 f4/thread; maximal decomposition
    kv_update_kernel<<<grid, block, 0, stream>>>(xk, xv, kpast, vpast, plen, out);
}